// Round 17
// baseline (199.816 us; speedup 1.0000x reference)
//
#include <hip/hip_runtime.h>
#include <hip/hip_bf16.h>

typedef __attribute__((ext_vector_type(8))) short short8;
typedef __attribute__((ext_vector_type(4))) float f32x4;

#define DEV __device__ __forceinline__

constexpr int Tn = 1024, Bn = 4, Dn = 1024, Rn = 64, Sn = 16, Mn = 64, Hn = 16;
constexpr int DH = 64;                 // head dim
constexpr int Qn = Rn + Tn + Sn;       // 1104 queries
constexpr int KL = Mn + Rn + Tn;       // 1152 keys
constexpr int NT = KL / 64;            // 18 key tiles
constexpr int NQB = 18;                // q-blocks of 64
constexpr int QB = Qn * Bn;            // 4416 q rows
constexpr int KB = KL * Bn;            // 4608 kv rows
constexpr int MU = 4672;               // unified rows: mems(256) rc(256) utt(4096) summ(64)
constexpr size_t OUTM = (size_t)(Rn + Tn) * Bn * Dn;   // 4,456,448
constexpr size_t OUTK = OUTM + (size_t)Sn * Bn * Dn;   // 4,521,984
constexpr size_t OUTV = OUTK + (size_t)Tn * Bn * Dn;   // 8,716,288
constexpr size_t NU  = (size_t)Tn * Bn * Dn;
constexpr size_t NR_ = (size_t)Rn * Bn * Dn;
constexpr size_t NS_ = (size_t)Sn * Bn * Dn;
constexpr size_t NM_ = (size_t)Mn * Bn * Dn;
constexpr float QSCALE = 0.18033688f;  // 0.125 * log2(e), folded into Q projection

DEV float b2f(ushort u) { union { unsigned v; float f; } x; x.v = ((unsigned)u) << 16; return x.f; }
DEV ushort f2b(float f) { __hip_bfloat16 h = __float2bfloat16(f); return *reinterpret_cast<ushort*>(&h); }

DEV float ldbias(const void* p, int i, int fp32) {
    return fp32 ? ((const float*)p)[i] : b2f(((const ushort*)p)[i]);
}
DEV void stout(void* p, size_t i, float v, int fp32) {
    if (fp32) ((float*)p)[i] = v; else ((ushort*)p)[i] = f2b(v);
}
DEV bool mread(const void* m, size_t idx, int mode) {
    if (mode == 0) return ((const unsigned char*)m)[idx] != 0;
    if (mode == 1) return ((const int*)m)[idx] != 0;
    return ((const float*)m)[idx] != 0.f;
}

DEV void gload_lds16(const void* g, void* l) {
    __builtin_amdgcn_global_load_lds(
        (const __attribute__((address_space(1))) unsigned int*)g,
        (__attribute__((address_space(3))) unsigned int*)l, 16, 0, 0);
}

DEV unsigned cvt_pk_bf16(float lo, float hi) {
    unsigned r;
    asm("v_cvt_pk_bf16_f32 %0, %1, %2" : "=v"(r) : "v"(lo), "v"(hi));
    return r;
}

// virtual key order: sigma(v) = (2*(v>>5) + ((v&7)>>2))*16 + ((v>>3)&3)*4 + (v&3)
DEV int sigma_key(int v) {
    return (2 * (v >> 5) + ((v & 7) >> 2)) * 16 + ((v >> 3) & 3) * 4 + (v & 3);
}

// ---------------------------------------------------------------- probe input dtypes
__global__ __launch_bounds__(256) void probe_kernel(const ushort* utt, const unsigned char* mask,
                                                    int* flags) {
    __shared__ int cnt[4];
    if (threadIdx.x < 4) cnt[threadIdx.x] = 0;
    __syncthreads();
    int c = 0;
    for (int i = threadIdx.x; i < 2048; i += 256) {
        int e = (utt[i] >> 7) & 0xFF;
        if (e > 64 && e < 192) c++;
    }
    atomicAdd(&cnt[0], c);
    int c0 = 0, c1 = 0, c23 = 0;
    for (int i = threadIdx.x; i < 8192; i += 256) {
        if (mask[i]) { int m = i & 3; if (m == 0) c0++; else if (m == 1) c1++; else c23++; }
    }
    atomicAdd(&cnt[1], c0); atomicAdd(&cnt[2], c1); atomicAdd(&cnt[3], c23);
    __syncthreads();
    if (threadIdx.x == 0) {
        flags[0] = (cnt[0] < 1900) ? 1 : 0;
        int mmode;
        if (cnt[2] == 0 && cnt[3] == 0) mmode = 1;
        else if (cnt[1] == 0) mmode = 2;
        else mmode = 0;
        flags[1] = mmode;
    }
}

// ---------------------------------------------------------------- bit-pack mask per (b, q, kt) with pad folded in
__global__ __launch_bounds__(256) void build_mbits(const void* __restrict__ amask,
                                                   const int* __restrict__ lengths,
                                                   unsigned long long* __restrict__ mbits,
                                                   const int* __restrict__ flags) {
    const int mmode = flags[1];
    int word = blockIdx.x * 4 + (threadIdx.x >> 6);
    if (word >= Bn * Qn * NT) return;
    int lane = threadIdx.x & 63;
    int ktl = word % NT;
    int rem = word / NT;
    int q = rem % Qn;
    int b = rem / Qn;
    const int l0 = lengths[0], l1 = lengths[1], l2 = lengths[2], l3 = lengths[3];
    const int maxlen = max(max(l0, l1), max(l2, l3));
    const int klen = lengths[b] + KL - maxlen;
    int kg = ktl * 64 + lane;
    bool m = mread(amask, (size_t)q * KL + kg, mmode) || (kg >= klen);
    unsigned long long bal = __ballot(m);
    if (lane == 0) mbits[word] = bal;
}

// ---------------------------------------------------------------- canonicalize activations -> bf16
__global__ __launch_bounds__(256) void convert_acts(const void* utt, const void* rc,
                                                    const void* sm, const void* mm,
                                                    ushort* dst, const int* flags) {
    const int fp32 = flags[0];
    const size_t total = (NU + NR_ + NS_ + NM_) / 8;
    for (size_t cidx = (size_t)blockIdx.x * 256 + threadIdx.x; cidx < total;
         cidx += (size_t)gridDim.x * 256) {
        size_t e = cidx * 8; const void* src; size_t li; ushort* d;
        if (e < NU)                  { src = utt; li = e;                 d = dst; }
        else if (e < NU + NR_)       { src = rc;  li = e - NU;            d = dst + NU; }
        else if (e < NU + NR_ + NS_) { src = sm;  li = e - NU - NR_;      d = dst + NU + NR_; }
        else                         { src = mm;  li = e - NU - NR_ - NS_; d = dst + NU + NR_ + NS_; }
        if (fp32) {
            const float* f = (const float*)src + li;
            ushort o[8];
#pragma unroll
            for (int j = 0; j < 8; ++j) o[j] = f2b(f[j]);
            *(short8*)(d + li) = *(short8*)o;
        } else {
            *(short8*)(d + li) = *(const short8*)((const ushort*)src + li);
        }
    }
}

// ---------------------------------------------------------------- transpose all W: (K x N) -> (N x K)
__global__ __launch_bounds__(256) void transpose_w3(const void* Wq, const void* Wkv, const void* Wout,
                                                    ushort* WqT, ushort* WkvT, ushort* WoutT,
                                                    const int* flags) {
    __shared__ alignas(16) ushort tile[64 * 64];
    const int fp32 = flags[0];
    const int z = blockIdx.z;
    const void* W; ushort* WT; int N;
    int tc = blockIdx.x, tr = blockIdx.y;
    if (z == 0)      { W = Wq;   WT = WqT;   N = 1024; }
    else if (z == 3) { W = Wout; WT = WoutT; N = 1024; }
    else             { W = Wkv;  WT = WkvT;  N = 2048; tc += (z - 1) * 16; }
    const int K = 1024;
    const int t = threadIdx.x;
    for (int c = t; c < 512; c += 256) {
        int row = c >> 3, q = c & 7;
        int u = q ^ (row & 7);
        ushort o[8];
#pragma unroll
        for (int j = 0; j < 8; ++j) {
            size_t gi = (size_t)(tr * 64 + row) * N + tc * 64 + q * 8 + j;
            o[j] = fp32 ? f2b(((const float*)W)[gi]) : ((const ushort*)W)[gi];
        }
        *(short8*)&tile[row * 64 + u * 8] = *(short8*)o;
    }
    __syncthreads();
    for (int c = t; c < 512; c += 256) {
        int n = c >> 3, q = c & 7;
        ushort vv[8];
#pragma unroll
        for (int j = 0; j < 8; ++j) {
            int k = q * 8 + j;
            int u = (n >> 3) ^ (k & 7);
            vv[j] = tile[k * 64 + u * 8 + (n & 7)];
        }
        *(short8*)(WT + (size_t)(tc * 64 + n) * K + tr * 64 + q * 8) = *(short8*)vv;
    }
}

// ---------------------------------------------------------------- transpose V: kv_ws -> vT[bh][d][sigma-ordered key]
__global__ __launch_bounds__(256) void transpose_v(const ushort* __restrict__ kv,
                                                   ushort* __restrict__ vT) {
    __shared__ alignas(16) ushort tile[64 * 64];
    const int kt = blockIdx.x, bh = blockIdx.y;
    const int b = bh >> 4, h = bh & 15;
    const int t = threadIdx.x;
    for (int c = t; c < 512; c += 256) {
        int key = c >> 3, q = c & 7;
        short8 v = *(const short8*)(kv + ((size_t)(kt * 64 + key) * Bn + b) * 2048 + 1024 + h * DH + q * 8);
        int u = q ^ (key & 7);
        *(short8*)&tile[key * 64 + u * 8] = v;
    }
    __syncthreads();
    for (int c = t; c < 512; c += 256) {
        int d = c >> 3, q = c & 7;
        ushort vv[8];
#pragma unroll
        for (int j = 0; j < 8; ++j) {
            int key = sigma_key(q * 8 + j);          // virtual -> actual key
            int u = (d >> 3) ^ (key & 7);
            vv[j] = tile[key * 64 + u * 8 + (d & 7)];
        }
        *(short8*)(vT + ((size_t)bh * 64 + d) * KL + kt * 64 + q * 8) = *(short8*)vv;
    }
}

// ---------------------------------------------------------------- fused QKV GEMM: 256x256, BK=64, 8 waves, 8-PHASE
// m201-style schedule: per K-tile 4 phases, each = {ds_read subtile ||
// 1 half-tile prefetch of kt+1 -> other buf || barrier, lgkmcnt(0), 16-MFMA
// setprio cluster, barrier}. bf hoisted once per tile (phase 0). Tile-ready
// wait = vmcnt(0) fused into phase 3's closing barrier (loads aged >=1 phase).
// LDS row-major [256][64] + 8-chunk XOR involution (measured conflict-free).
#define Q8_STAGE_A(BUF, KT, HALF)                                                     \
    _Pragma("unroll")                                                                 \
    for (int i2 = 0; i2 < 2; ++i2)                                                    \
        gload_lds16(asrc2[HALF][i2] + (KT) * 64, &As[BUF][(HALF) * 8192 + (i2 * 512 + t) * 8]);
#define Q8_STAGE_B(BUF, KT, HALF)                                                     \
    _Pragma("unroll")                                                                 \
    for (int i2 = 0; i2 < 2; ++i2)                                                    \
        gload_lds16(bsrc2[HALF][i2] + (KT) * 64, &Bs[BUF][(HALF) * 8192 + (i2 * 512 + t) * 8]);

#define Q8_RD_AF(BUF, P)                                                              \
    _Pragma("unroll")                                                                 \
    for (int mq = 0; mq < 2; ++mq)                                                    \
        _Pragma("unroll")                                                             \
        for (int ks = 0; ks < 2; ++ks) {                                              \
            int r_ = wr * 128 + (P) * 32 + mq * 16 + lr;                              \
            af[mq][ks] = *(const short8*)&As[BUF][r_ * 64 + (((ks * 4 + g) ^ (r_ & 7)) << 3)]; \
        }

#define Q8_MM(P)                                                                      \
    __builtin_amdgcn_s_barrier();                                                     \
    asm volatile("s_waitcnt lgkmcnt(0)" ::: "memory");                                \
    __builtin_amdgcn_sched_barrier(0);                                                \
    __builtin_amdgcn_s_setprio(1);                                                    \
    _Pragma("unroll")                                                                 \
    for (int mq = 0; mq < 2; ++mq)                                                    \
        _Pragma("unroll")                                                             \
        for (int n = 0; n < 4; ++n) {                                                 \
            acc[(P) * 2 + mq][n] = __builtin_amdgcn_mfma_f32_16x16x32_bf16(af[mq][0], bfr[n][0], acc[(P) * 2 + mq][n], 0, 0, 0); \
            acc[(P) * 2 + mq][n] = __builtin_amdgcn_mfma_f32_16x16x32_bf16(af[mq][1], bfr[n][1], acc[(P) * 2 + mq][n], 0, 0, 0); \
        }                                                                             \
    __builtin_amdgcn_s_setprio(0);

__global__ __launch_bounds__(512, 1) void gemm_qkv(
    const ushort* __restrict__ cmem, const ushort* __restrict__ crc,
    const ushort* __restrict__ cutt, const ushort* __restrict__ csum,
    const ushort* __restrict__ Bt, const void* __restrict__ bq, const void* __restrict__ bkv,
    ushort* __restrict__ q_ws, ushort* __restrict__ kv_ws,
    void* __restrict__ gout, const int* __restrict__ flags) {
    __shared__ alignas(16) ushort As[2][16384];   // [256][64] x2 = 64 KB
    __shared__ alignas(16) ushort Bs[2][16384];   // 64 KB
    const int ofp = flags[0];
    const int t = threadIdx.x;
    const int lane = t & 63;
    const int w = t >> 6;
    const int wr = w >> 2, wc = w & 3;            // 2M x 4N waves
    const int g = lane >> 4, lr = lane & 15;

    // bijective XCD swizzle for 228 blocks (= 8*28 + 4): q=28, r=4
    const int bid = blockIdx.x;
    const int xcd = bid & 7, idx = bid >> 3;
    const int wg = (xcd < 4 ? xcd * 29 : 116 + (xcd - 4) * 28) + idx;
    const int bx = wg % 12, by = wg / 12;
    const int mbase = by * 256, nbase = bx * 256;

    // staging sources per [half][i2]: slot = i2*512 + t; local row = slot>>3, kc = slot&7
    const ushort* asrc2[2][2]; const ushort* bsrc2[2][2];
#pragma unroll
    for (int half = 0; half < 2; ++half)
#pragma unroll
        for (int i2 = 0; i2 < 2; ++i2) {
            int slot = i2 * 512 + t;
            int row = slot >> 3, kc = slot & 7;
            int q = kc ^ (row & 7);
            int grow = mbase + half * 128 + row;
            if (grow >= MU) grow = MU - 1;
            const ushort* s;
            if (grow < 256)       s = cmem + (size_t)grow * 1024;
            else if (grow < 512)  s = crc + (size_t)(grow - 256) * 1024;
            else if (grow < 4608) s = cutt + (size_t)(grow - 512) * 1024;
            else                  s = csum + (size_t)(grow - 4608) * 1024;
            asrc2[half][i2] = s + q * 8;
            bsrc2[half][i2] = Bt + (size_t)(nbase + half * 128 + row) * 1024 + q * 8;
        }

    f32x4 acc[8][4] = {};
    short8 bfr[4][2], af[2][2];

    // prologue: stage tile 0 fully, drain, barrier
    Q8_STAGE_A(0, 0, 0); Q8_STAGE_A(0, 0, 1);
    Q8_STAGE_B(0, 0, 0); Q8_STAGE_B(0, 0, 1);
    asm volatile("s_waitcnt vmcnt(0)" ::: "memory");
    __builtin_amdgcn_sched_barrier(0);
    __builtin_amdgcn_s_barrier();

    for (int kt = 0; kt < 16; ++kt) {
        const int c = kt & 1, o = c ^ 1;
        const bool pre = (kt + 1 < 16);

        // ---- phase 0: bf (8 reads) + af q0 (4 reads); prefetch A-half0
#pragma unroll
        for (int n = 0; n < 4; ++n)
#pragma unroll
            for (int ks = 0; ks < 2; ++ks) {
                int r_ = wc * 64 + n * 16 + lr;
                bfr[n][ks] = *(const short8*)&Bs[c][r_ * 64 + (((ks * 4 + g) ^ (r_ & 7)) << 3)];
            }
        Q8_RD_AF(c, 0);
        if (pre) { Q8_STAGE_A(o, kt + 1, 0); }
        Q8_MM(0);
        __builtin_amdgcn_s_barrier();

        // ---- phase 1: af q1; prefetch A-half1
        Q8_RD_AF(c, 1);
        if (pre) { Q8_STAGE_A(o, kt + 1, 1); }
        Q8_MM(1);
        __builtin_amdgcn_s_barrier();

        // ---- phase 2: af q2; prefetch B-half0
        Q8_RD_AF(c, 2);
        if (pre) { Q8_STAGE_B(o, kt + 1, 0); }
        Q8_MM(2);
        __builtin_amdgcn_s_barrier();

        // ---- phase 3: af q3; prefetch B-half1; close = vmcnt(0) + barrier
        Q8_RD_AF(c, 3);
        if (pre) { Q8_STAGE_B(o, kt + 1, 1); }
        Q8_MM(3);
        asm volatile("s_waitcnt vmcnt(0)" ::: "memory");
        __builtin_amdgcn_sched_barrier(0);
        __builtin_amdgcn_s_barrier();
    }

#pragma unroll
    for (int n = 0; n < 4; ++n) {
        int col = nbase + wc * 64 + n * 16 + lr;
        float bv = (col < 1024) ? ldbias(bq, col, ofp) : ldbias(bkv, col - 1024, ofp);
#pragma unroll
        for (int m = 0; m < 8; ++m) {
            int rowb = mbase + wr * 128 + m * 16 + g * 4;
#pragma unroll
            for (int i = 0; i < 4; ++i) {
                int r = rowb + i;
                if (r >= MU) continue;
                float val = acc[m][n][i] + bv;
                if (col < 1024) {
                    if (r >= 256) q_ws[(size_t)(r - 256) * 1024 + col] = f2b(val * QSCALE);
                } else {
                    if (r < 4608) {
                        kv_ws[(size_t)r * 2048 + (col - 1024)] = f2b(val);
                        if (r >= 512) {
                            size_t o2 = (col < 2048)
                                ? OUTK + (size_t)(r - 512) * 1024 + (col - 1024)
                                : OUTV + (size_t)(r - 512) * 1024 + (col - 2048);
                            stout(gout, o2, val, ofp);
                        }
                    }
                }
            }
        }
    }
}

// ---------------------------------------------------------------- out GEMM: 64x128 tile, BK=64, 4 waves
// 48KB LDS -> 3 blocks/CU; k-contiguous 128B staging; counted vmcnt(6).
#define O_STAGE(DSTBUF, KT)                                                           \
    _Pragma("unroll")                                                                 \
    for (int i2 = 0; i2 < 2; ++i2)                                                    \
        gload_lds16(asrc[i2] + (KT) * 64, &As[DSTBUF][(i2 * 256 + t) * 8]);           \
    _Pragma("unroll")                                                                 \
    for (int i2 = 0; i2 < 4; ++i2)                                                    \
        gload_lds16(bsrc[i2] + (KT) * 64, &Bs[DSTBUF][(i2 * 256 + t) * 8]);

__global__ __launch_bounds__(256, 3) void gemm_out(
    const ushort* __restrict__ A, const ushort* __restrict__ Bt,
    const void* __restrict__ bias, void* __restrict__ gout, const int* __restrict__ flags) {
    __shared__ alignas(16) ushort As[2][4096];   // [64][64] x2 = 16 KB
    __shared__ alignas(16) ushort Bs[2][8192];   // [128][64] x2 = 32 KB
    const int ofp = flags[0];
    const int t = threadIdx.x;
    const int lane = t & 63;
    const int w = t >> 6;
    const int wr = w >> 1, wc = w & 1;
    const int g = lane >> 4, lr = lane & 15;

    const int nwg = gridDim.x;                   // 552, %8 == 0
    const int bid = blockIdx.x;
    const int wg = (bid & 7) * (nwg >> 3) + (bid >> 3);
    const int bx = wg % 8, by = wg / 8;
    const int mbase = by * 64, nbase = bx * 128;   // 69*64 = 4416 exact

    const ushort* asrc[2];
#pragma unroll
    for (int i2 = 0; i2 < 2; ++i2) {
        int slot = i2 * 256 + t;
        int row = slot >> 3, kc = slot & 7, q = kc ^ (row & 7);
        asrc[i2] = A + (size_t)(mbase + row) * 1024 + q * 8;
    }
    const ushort* bsrc[4];
#pragma unroll
    for (int i2 = 0; i2 < 4; ++i2) {
        int slot = i2 * 256 + t;
        int row = slot >> 3, kc = slot & 7, q = kc ^ (row & 7);
        bsrc[i2] = Bt + (size_t)(nbase + row) * 1024 + q * 8;
    }

    f32x4 acc[2][4] = {};

    O_STAGE(0, 0);

    for (int kt = 0; kt < 16; ++kt) {
        const int c = kt & 1;
        if (kt + 1 < 16) {
            O_STAGE(c ^ 1, kt + 1);
            asm volatile("s_waitcnt vmcnt(6)" ::: "memory");
        } else {
            asm volatile("s_waitcnt vmcnt(0)" ::: "memory");
        }
        __builtin_amdgcn_sched_barrier(0);
        __builtin_amdgcn_s_barrier();

        short8 bfr[4][2];
#pragma unroll
        for (int n = 0; n < 4; ++n)
#pragma unroll
            for (int ks = 0; ks < 2; ++ks) {
                int col = wc * 64 + n * 16 + lr;
                bfr[n][ks] = *(const short8*)&Bs[c][col * 64 + (((ks * 4 + g) ^ (lr & 7)) << 3)];
            }
        short8 af[2][2];
#pragma unroll
        for (int m = 0; m < 2; ++m)
#pragma unroll
            for (int ks = 0; ks < 2; ++ks) {
                int row = wr * 32 + m * 16 + lr;
                af[m][ks] = *(const short8*)&As[c][row * 64 + (((ks * 4 + g) ^ (lr & 7)) << 3)];
            }
        __builtin_amdgcn_s_setprio(1);
#pragma unroll
        for (int m = 0; m < 2; ++m)
#pragma unroll
            for (int n = 0; n < 4; ++n) {
                acc[m][n] = __builtin_amdgcn_mfma_f32_16x16x32_bf16(af[m][0], bfr[n][0], acc[m][n], 0, 0, 0);
                acc[m][n] = __builtin_amdgcn_mfma_f32_16x16x32_bf16(af[m][1], bfr[n][1], acc[m][n], 0, 0, 0);
            }
        __builtin_amdgcn_s_setprio(0);

        __builtin_amdgcn_sched_barrier(0);
        __builtin_amdgcn_s_barrier();
    }

#pragma unroll
    for (int n = 0; n < 4; ++n) {
        int col = nbase + wc * 64 + n * 16 + lr;
        float bv = ldbias(bias, col, ofp);
#pragma unroll
        for (int m = 0; m < 2; ++m) {
            int rowb = mbase + wr * 32 + m * 16 + g * 4;
#pragma unroll
            for (int i = 0; i < 4; ++i) {
                int row = rowb + i;
                float val = acc[m][n][i] + bv;
                if (row < (Rn + Tn) * Bn) stout(gout, (size_t)row * 1024 + col, val, ofp);
                else stout(gout, OUTM + (size_t)(row - (Rn + Tn) * Bn) * 1024 + col, tanhf(val), ofp);
            }
        }
    }
}

// ---------------------------------------------------------------- attention (unchanged)
#define ATTN_STAGE(DSTBUF, KT)                                                        \
    gload_lds16(ksrc0 + (size_t)(KT) * kstep, &Ks[DSTBUF][w * 1024]);                 \
    gload_lds16(ksrc1 + (size_t)(KT) * kstep, &Ks[DSTBUF][w * 1024 + 512]);           \
    gload_lds16(vsrc0 + (size_t)(KT) * 64,    &Vs[DSTBUF][w * 1024]);                 \
    gload_lds16(vsrc1 + (size_t)(KT) * 64,    &Vs[DSTBUF][w * 1024 + 512]);

#define ATTN_PHASE(CUR, WBCUR, PRE, KTN, WBNXT, VMSTR)                                \
    {                                                                                 \
        if (PRE) { ATTN_STAGE((CUR) ^ 1, KTN); WBNXT = mp[KTN]; }                     \
        asm volatile("s_waitcnt " VMSTR ::: "memory");                                \
        __builtin_amdgcn_sched_barrier(0);                                            \
        __builtin_amdgcn_s_barrier();                                                 \
        __builtin_amdgcn_sched_barrier(0);                                            \
        f32x4 sa[4] = {};                                                             \
        __builtin_amdgcn_s_setprio(1);                                                \
        _Pragma("unroll")                                                             \
        for (int n = 0; n < 4; ++n) {                                                 \
            int key = n * 16 + lr;                                                    \
            short8 kb0 = *(const short8*)&Ks[CUR][key * 64 + ((g ^ (key & 7)) << 3)]; \
            short8 kb1 = *(const short8*)&Ks[CUR][key * 64 + (((4 + g) ^ (key & 7)) << 3)]; \
            sa[n] = __builtin_amdgcn_mfma_f32_16x16x32_bf16(kb0, qf0, sa[n], 0, 0, 0); \
            sa[n] = __builtin_amdgcn_mfma_f32_16x16x32_bf16(kb1, qf1, sa[n], 0, 0, 0); \
        }                                                                             \
        __builtin_amdgcn_s_setprio(0);                                                \
        unsigned pkk[4][2];                                                           \
        _Pragma("unroll")                                                             \
        for (int n = 0; n < 4; ++n) {                                                 \
            unsigned bits = (unsigned)((WBCUR) >> (n * 16 + g * 4)) & 15u;            \
            float p[4];                                                               \
            _Pragma("unroll")                                                         \
            for (int i = 0; i < 4; ++i) {                                             \
                float sv = ((bits >> i) & 1u) ? -100.0f : sa[n][i];                   \
                p[i] = exp2f(sv);                                                     \
                lsum += p[i];                                                         \
            }                                                                         \
            pkk[n][0] = cvt_pk_bf16(p[0], p[1]);                                      \
            pkk[n][1] = cvt_pk_bf16(p[2], p[3]);                                      \
        }                                                                             \
        union { unsigned u[4]; short8 s; } c0, c1;                                    \
        c0.u[0] = pkk[0][0]; c0.u[1] = pkk[0][1]; c0.u[2] = pkk[1][0]; c0.u[3] = pkk[1][1]; \
        c1.u[0] = pkk[2][0]; c1.u[1] = pkk[2][1]; c1.u[2] = pkk[3][0]; c1.u[3] = pkk[3][1]; \
        __builtin_amdgcn_s_setprio(1);                                                \
        _Pragma("unroll")                                                             \
        for (int n = 0; n < 4; ++n) {                                                 \
            int d = n * 16 + lr;                                                      \
            short8 vb0 = *(const short8*)&Vs[CUR][d * 64 + ((g ^ (d & 7)) << 3)];     \
            short8 vb1 = *(const short8*)&Vs[CUR][d * 64 + (((4 + g) ^ (d & 7)) << 3)]; \
            acc_o[n] = __builtin_amdgcn_mfma_f32_16x16x32_bf16(c0.s, vb0, acc_o[n], 0, 0, 0); \
            acc_o[n] = __builtin_amdgcn_mfma_f32_16x16x32_bf16(c1.s, vb1, acc_o[n], 0, 0, 0); \
        }                                                                             \
        __builtin_amdgcn_s_setprio(0);                                                \
        __builtin_amdgcn_sched_barrier(0);                                            \
        __builtin_amdgcn_s_barrier();                                                 \
    }

__global__ __launch_bounds__(256, 5) void attn_kernel(
    const ushort* __restrict__ qws, const ushort* __restrict__ kvws, const ushort* __restrict__ vTws,
    const unsigned long long* __restrict__ mbits,
    ushort* __restrict__ attnws) {
    __shared__ alignas(16) ushort Ks[2][64 * 64];
    __shared__ alignas(16) ushort Vs[2][64 * 64];

    const int bid = blockIdx.x;
    const int wg = (bid & 7) * (gridDim.x >> 3) + (bid >> 3);
    const int qblk = wg % NQB;
    const int bh = wg / NQB;
    const int b = bh >> 4, h = bh & 15;
    const int t = threadIdx.x;
    const int w = t >> 6, lane = t & 63;
    const int g = lane >> 4, lr = lane & 15;

    const int qi = qblk * 64 + w * 16 + lr;
    const int qic = qi < Qn ? qi : (Qn - 1);
    const ushort* qptr = qws + ((size_t)qic * Bn + b) * Dn + h * DH;
    const short8 qf0 = *(const short8*)(qptr + g * 8);
    const short8 qf1 = *(const short8*)(qptr + 32 + g * 8);
    const unsigned long long* mp = mbits + ((size_t)b * Qn + qic) * NT;

    const int srow0 = w * 16 + (lane >> 3);
    const int srow1 = srow0 + 8;
    const int sw = (((lane & 7) ^ ((lane >> 3) & 7)) << 3);
    const ushort* ksrc0 = kvws + ((size_t)srow0 * Bn + b) * 2048 + h * DH + sw;
    const ushort* ksrc1 = kvws + ((size_t)srow1 * Bn + b) * 2048 + h * DH + sw;
    const ushort* vsrc0 = vTws + ((size_t)bh * 64 + srow0) * KL + sw;
    const ushort* vsrc1 = vTws + ((size_t)bh * 64 + srow1) * KL + sw;
    const size_t kstep = (size_t)64 * Bn * 2048;

    f32x4 acc_o[4] = {};
    float lsum = 0.f;
    unsigned long long wbA, wbB;

    ATTN_STAGE(0, 0);
    wbA = mp[0];
    wbB = 0;

    for (int kt2 = 0; kt2 < NT - 2; kt2 += 2) {
        ATTN_PHASE(0, wbA, true, kt2 + 1, wbB, "vmcnt(5)");
        ATTN_PHASE(1, wbB, true, kt2 + 2, wbA, "vmcnt(5)");
    }
    ATTN_PHASE(0, wbA, true, NT - 1, wbB, "vmcnt(5)");
    ATTN_PHASE(1, wbB, false, 0, wbA, "vmcnt(0)");

    float ls = lsum;
    ls += __shfl_xor(ls, 16);
    ls += __shfl_xor(ls, 32);
#pragma unroll
    for (int i = 0; i < 4; ++i) {
        int qrow = g * 4 + i;
        float lsv = __shfl(ls, (lane & 48) | qrow);
        int qg = qblk * 64 + w * 16 + qrow;
        if (qg >= Qn) continue;
        float inv = 1.f / lsv;
#pragma unroll
        for (int n = 0; n < 4; ++n) {
            attnws[((size_t)qg * Bn + b) * Dn + h * DH + n * 16 + lr] = f2b(acc_o[n][i] * inv);
        }
    }
}

// ---------------------------------------------------------------- launch
extern "C" void kernel_launch(void* const* d_in, const int* in_sizes, int n_in,
                              void* d_out, int out_size, void* d_ws, size_t ws_size,
                              hipStream_t stream) {
    const void* utt   = d_in[0];
    const void* rc    = d_in[1];
    const void* summ  = d_in[2];
    const void* mems  = d_in[3];
    const int*  lens  = (const int*)d_in[4];
    const void* amask = d_in[5];
    const void* Wq   = d_in[6];
    const void* bq   = d_in[7];
    const void* Wkv  = d_in[8];
    const void* bkv  = d_in[9];
    const void* Wout = d_in[10];
    const void* bout = d_in[11];

    ushort* ws    = (ushort*)d_ws;
    int*   flags  = (int*)d_ws;
    ushort* cu    = ws + 64;
    ushort* cutt  = cu;
    ushort* crc   = cutt + NU;
    ushort* csum  = crc + NR_;
    ushort* cmem  = csum + NS_;
    ushort* WqT   = cmem + NM_;                      // WqT then WkvT contiguous = fused (3072 x 1024) Bt
    ushort* WkvT  = WqT + (size_t)1024 * 1024;
    ushort* WoutT = WkvT + (size_t)2048 * 1024;
    ushort* q_ws  = WoutT + (size_t)1024 * 1024;
    ushort* kv_ws = q_ws + (size_t)QB * Dn;
    ushort* vT_ws = kv_ws + (size_t)KB * 2048;
    ushort* at_ws = vT_ws + (size_t)64 * 64 * KL;
    unsigned long long* mbits = (unsigned long long*)(at_ws + (size_t)QB * Dn);  // Bn*Qn*NT words

    probe_kernel<<<1, 256, 0, stream>>>((const ushort*)utt, (const unsigned char*)amask, flags);
    build_mbits<<<(Bn * Qn * NT + 3) / 4, 256, 0, stream>>>(amask, lens, mbits, flags);
    convert_acts<<<1024, 256, 0, stream>>>(utt, rc, summ, mems, cu, flags);
    transpose_w3<<<dim3(16, 16, 4), 256, 0, stream>>>(Wq, Wkv, Wout, WqT, WkvT, WoutT, flags);

    gemm_qkv<<<dim3(228), 512, 0, stream>>>(cmem, crc, cutt, csum, WqT, bq, bkv,
                                            q_ws, kv_ws, d_out, flags);
    transpose_v<<<dim3(KL / 64, Bn * Hn), 256, 0, stream>>>(kv_ws, vT_ws);
    attn_kernel<<<dim3(NQB * Bn * Hn), 256, 0, stream>>>(q_ws, kv_ws, vT_ws, mbits, at_ws);
    gemm_out<<<dim3(552), 256, 0, stream>>>(at_ws, WoutT, bout, d_out, flags);
}

// Round 18
// 175.222 us; speedup vs baseline: 1.1404x; 1.1404x over previous
//
#include <hip/hip_runtime.h>
#include <hip/hip_bf16.h>

typedef __attribute__((ext_vector_type(8))) short short8;
typedef __attribute__((ext_vector_type(4))) float f32x4;

#define DEV __device__ __forceinline__

constexpr int Tn = 1024, Bn = 4, Dn = 1024, Rn = 64, Sn = 16, Mn = 64, Hn = 16;
constexpr int DH = 64;                 // head dim
constexpr int Qn = Rn + Tn + Sn;       // 1104 queries
constexpr int KL = Mn + Rn + Tn;       // 1152 keys
constexpr int NT = KL / 64;            // 18 key tiles
constexpr int NQB = 18;                // q-blocks of 64
constexpr int QB = Qn * Bn;            // 4416 q rows
constexpr int KB = KL * Bn;            // 4608 kv rows
constexpr int MU = 4672;               // unified rows: mems(256) rc(256) utt(4096) summ(64)
constexpr size_t OUTM = (size_t)(Rn + Tn) * Bn * Dn;   // 4,456,448
constexpr size_t OUTK = OUTM + (size_t)Sn * Bn * Dn;   // 4,521,984
constexpr size_t OUTV = OUTK + (size_t)Tn * Bn * Dn;   // 8,716,288
constexpr size_t NU  = (size_t)Tn * Bn * Dn;
constexpr size_t NR_ = (size_t)Rn * Bn * Dn;
constexpr size_t NS_ = (size_t)Sn * Bn * Dn;
constexpr size_t NM_ = (size_t)Mn * Bn * Dn;
constexpr float QSCALE = 0.18033688f;  // 0.125 * log2(e), folded into Q projection

constexpr int PREP_TW = 1024;                          // transpose_w3 sub-grid
constexpr int PREP_CV = 1024;                          // convert_acts sub-grid
constexpr int PREP_MB = (Bn * Qn * NT + 3) / 4;        // build_mbits sub-grid (19872)

DEV float b2f(ushort u) { union { unsigned v; float f; } x; x.v = ((unsigned)u) << 16; return x.f; }
DEV ushort f2b(float f) { __hip_bfloat16 h = __float2bfloat16(f); return *reinterpret_cast<ushort*>(&h); }

DEV float ldbias(const void* p, int i, int fp32) {
    return fp32 ? ((const float*)p)[i] : b2f(((const ushort*)p)[i]);
}
DEV void stout(void* p, size_t i, float v, int fp32) {
    if (fp32) ((float*)p)[i] = v; else ((ushort*)p)[i] = f2b(v);
}
DEV bool mread(const void* m, size_t idx, int mode) {
    if (mode == 0) return ((const unsigned char*)m)[idx] != 0;
    if (mode == 1) return ((const int*)m)[idx] != 0;
    return ((const float*)m)[idx] != 0.f;
}

DEV void gload_lds16(const void* g, void* l) {
    __builtin_amdgcn_global_load_lds(
        (const __attribute__((address_space(1))) unsigned int*)g,
        (__attribute__((address_space(3))) unsigned int*)l, 16, 0, 0);
}

DEV unsigned cvt_pk_bf16(float lo, float hi) {
    unsigned r;
    asm("v_cvt_pk_bf16_f32 %0, %1, %2" : "=v"(r) : "v"(lo), "v"(hi));
    return r;
}

// virtual key order: sigma(v) = (2*(v>>5) + ((v&7)>>2))*16 + ((v>>3)&3)*4 + (v&3)
DEV int sigma_key(int v) {
    return (2 * (v >> 5) + ((v & 7) >> 2)) * 16 + ((v >> 3) & 3) * 4 + (v & 3);
}

// ---------------------------------------------------------------- probe input dtypes
__global__ __launch_bounds__(256) void probe_kernel(const ushort* utt, const unsigned char* mask,
                                                    int* flags) {
    __shared__ int cnt[4];
    if (threadIdx.x < 4) cnt[threadIdx.x] = 0;
    __syncthreads();
    int c = 0;
    for (int i = threadIdx.x; i < 2048; i += 256) {
        int e = (utt[i] >> 7) & 0xFF;
        if (e > 64 && e < 192) c++;
    }
    atomicAdd(&cnt[0], c);
    int c0 = 0, c1 = 0, c23 = 0;
    for (int i = threadIdx.x; i < 8192; i += 256) {
        if (mask[i]) { int m = i & 3; if (m == 0) c0++; else if (m == 1) c1++; else c23++; }
    }
    atomicAdd(&cnt[1], c0); atomicAdd(&cnt[2], c1); atomicAdd(&cnt[3], c23);
    __syncthreads();
    if (threadIdx.x == 0) {
        flags[0] = (cnt[0] < 1900) ? 1 : 0;
        int mmode;
        if (cnt[2] == 0 && cnt[3] == 0) mmode = 1;
        else if (cnt[1] == 0) mmode = 2;
        else mmode = 0;
        flags[1] = mmode;
    }
}

// ---------------------------------------------------------------- merged prep kernel
// block ranges: [0,1024) transpose_w3 | [1024,2048) convert_acts | rest build_mbits
__global__ __launch_bounds__(256) void prep_kernel(
    const void* utt, const void* rc, const void* sm, const void* mm,
    const void* Wq, const void* Wkv, const void* Wout,
    const void* amask, const int* __restrict__ lengths,
    ushort* dst, ushort* WqT, ushort* WkvT, ushort* WoutT,
    unsigned long long* __restrict__ mbits, const int* __restrict__ flags) {
    __shared__ alignas(16) ushort tile[64 * 64];
    const int fp32 = flags[0];
    const int t = threadIdx.x;
    int bid = blockIdx.x;

    if (bid < PREP_TW) {
        // ---- transpose W: (K x N) -> (N x K)
        const int z = bid >> 8, tr = (bid >> 4) & 15;
        int tc = bid & 15;
        const void* W; ushort* WT; int N;
        if (z == 0)      { W = Wq;   WT = WqT;   N = 1024; }
        else if (z == 3) { W = Wout; WT = WoutT; N = 1024; }
        else             { W = Wkv;  WT = WkvT;  N = 2048; tc += (z - 1) * 16; }
        const int K = 1024;
        for (int c = t; c < 512; c += 256) {
            int row = c >> 3, q = c & 7;
            int u = q ^ (row & 7);
            ushort o[8];
#pragma unroll
            for (int j = 0; j < 8; ++j) {
                size_t gi = (size_t)(tr * 64 + row) * N + tc * 64 + q * 8 + j;
                o[j] = fp32 ? f2b(((const float*)W)[gi]) : ((const ushort*)W)[gi];
            }
            *(short8*)&tile[row * 64 + u * 8] = *(short8*)o;
        }
        __syncthreads();
        for (int c = t; c < 512; c += 256) {
            int n = c >> 3, q = c & 7;
            ushort vv[8];
#pragma unroll
            for (int j = 0; j < 8; ++j) {
                int k = q * 8 + j;
                int u = (n >> 3) ^ (k & 7);
                vv[j] = tile[k * 64 + u * 8 + (n & 7)];
            }
            *(short8*)(WT + (size_t)(tc * 64 + n) * K + tr * 64 + q * 8) = *(short8*)vv;
        }
        return;
    }
    bid -= PREP_TW;
    if (bid < PREP_CV) {
        // ---- canonicalize activations -> bf16
        const size_t total = (NU + NR_ + NS_ + NM_) / 8;
        for (size_t cidx = (size_t)bid * 256 + t; cidx < total;
             cidx += (size_t)PREP_CV * 256) {
            size_t e = cidx * 8; const void* src; size_t li; ushort* d;
            if (e < NU)                  { src = utt; li = e;                 d = dst; }
            else if (e < NU + NR_)       { src = rc;  li = e - NU;            d = dst + NU; }
            else if (e < NU + NR_ + NS_) { src = sm;  li = e - NU - NR_;      d = dst + NU + NR_; }
            else                         { src = mm;  li = e - NU - NR_ - NS_; d = dst + NU + NR_ + NS_; }
            if (fp32) {
                const float* f = (const float*)src + li;
                ushort o[8];
#pragma unroll
                for (int j = 0; j < 8; ++j) o[j] = f2b(f[j]);
                *(short8*)(d + li) = *(short8*)o;
            } else {
                *(short8*)(d + li) = *(const short8*)((const ushort*)src + li);
            }
        }
        return;
    }
    bid -= PREP_CV;
    // ---- bit-pack mask per (b, q, kt) with pad folded in
    const int mmode = flags[1];
    int word = bid * 4 + (t >> 6);
    if (word >= Bn * Qn * NT) return;
    int lane = t & 63;
    int ktl = word % NT;
    int rem = word / NT;
    int q = rem % Qn;
    int b = rem / Qn;
    const int l0 = lengths[0], l1 = lengths[1], l2 = lengths[2], l3 = lengths[3];
    const int maxlen = max(max(l0, l1), max(l2, l3));
    const int klen = lengths[b] + KL - maxlen;
    int kg = ktl * 64 + lane;
    bool m = mread(amask, (size_t)q * KL + kg, mmode) || (kg >= klen);
    unsigned long long bal = __ballot(m);
    if (lane == 0) mbits[word] = bal;
}

// ---------------------------------------------------------------- transpose V: kv_ws -> vT[bh][d][sigma-ordered key]
__global__ __launch_bounds__(256) void transpose_v(const ushort* __restrict__ kv,
                                                   ushort* __restrict__ vT) {
    __shared__ alignas(16) ushort tile[64 * 64];
    const int kt = blockIdx.x, bh = blockIdx.y;
    const int b = bh >> 4, h = bh & 15;
    const int t = threadIdx.x;
    for (int c = t; c < 512; c += 256) {
        int key = c >> 3, q = c & 7;
        short8 v = *(const short8*)(kv + ((size_t)(kt * 64 + key) * Bn + b) * 2048 + 1024 + h * DH + q * 8);
        int u = q ^ (key & 7);
        *(short8*)&tile[key * 64 + u * 8] = v;
    }
    __syncthreads();
    for (int c = t; c < 512; c += 256) {
        int d = c >> 3, q = c & 7;
        ushort vv[8];
#pragma unroll
        for (int j = 0; j < 8; ++j) {
            int key = sigma_key(q * 8 + j);          // virtual -> actual key
            int u = (d >> 3) ^ (key & 7);
            vv[j] = tile[key * 64 + u * 8 + (d & 7)];
        }
        *(short8*)(vT + ((size_t)bh * 64 + d) * KL + kt * 64 + q * 8) = *(short8*)vv;
    }
}

// ---------------------------------------------------------------- fused QKV GEMM, 128x128 tile, BK=64, 4 waves
// 888 blocks, 64KB LDS -> 2 blocks/CU. k-contiguous 128B staging
// (row = slot>>3, 8-chunk XOR involution), counted vmcnt(8) 2-phase.
#define Q128_STAGE(DSTBUF, KT)                                                        \
    _Pragma("unroll")                                                                 \
    for (int i2 = 0; i2 < 4; ++i2) {                                                  \
        gload_lds16(asrc[i2] + (KT) * 64, &As[DSTBUF][(i2 * 256 + t) * 8]);           \
        gload_lds16(bsrc[i2] + (KT) * 64, &Bs[DSTBUF][(i2 * 256 + t) * 8]);           \
    }

__global__ __launch_bounds__(256, 2) void gemm_qkv(
    const ushort* __restrict__ cmem, const ushort* __restrict__ crc,
    const ushort* __restrict__ cutt, const ushort* __restrict__ csum,
    const ushort* __restrict__ Bt, const void* __restrict__ bq, const void* __restrict__ bkv,
    ushort* __restrict__ q_ws, ushort* __restrict__ kv_ws,
    void* __restrict__ gout, const int* __restrict__ flags) {
    __shared__ alignas(16) ushort As[2][8192];   // [128 rows][64 k] x2 = 32 KB
    __shared__ alignas(16) ushort Bs[2][8192];   // 32 KB
    const int ofp = flags[0];
    const int t = threadIdx.x;
    const int lane = t & 63;
    const int w = t >> 6;
    const int wr = w >> 1, wc = w & 1;            // 2M x 2N wave grid
    const int g = lane >> 4, lr = lane & 15;

    // XCD swizzle: nwg = 37*24 = 888, %8 == 0
    const int bid = blockIdx.x;
    const int wg = (bid & 7) * 111 + (bid >> 3);
    const int bx = wg % 24, by = wg / 24;
    const int mbase = by * 128, nbase = bx * 128;

    // staging: slot = i2*256 + t; row = slot>>3 (0..127), kc = slot&7,
    // src chunk q = kc^(row&7)  (XOR involution within one 128B k-row)
    const ushort* asrc[4]; const ushort* bsrc[4];
#pragma unroll
    for (int i2 = 0; i2 < 4; ++i2) {
        int slot = i2 * 256 + t;
        int row = slot >> 3, kc = slot & 7;
        int q = kc ^ (row & 7);
        int grow = mbase + row;
        if (grow >= MU) grow = MU - 1;
        const ushort* s;
        if (grow < 256)       s = cmem + (size_t)grow * 1024;
        else if (grow < 512)  s = crc + (size_t)(grow - 256) * 1024;
        else if (grow < 4608) s = cutt + (size_t)(grow - 512) * 1024;
        else                  s = csum + (size_t)(grow - 4608) * 1024;
        asrc[i2] = s + q * 8;
        bsrc[i2] = Bt + (size_t)(nbase + row) * 1024 + q * 8;
    }

    f32x4 acc[4][4] = {};

    Q128_STAGE(0, 0);

    for (int kt = 0; kt < 16; ++kt) {
        const int c = kt & 1;
        if (kt + 1 < 16) {
            Q128_STAGE(c ^ 1, kt + 1);
            asm volatile("s_waitcnt vmcnt(8)" ::: "memory");   // tile kt done; kt+1 in flight
        } else {
            asm volatile("s_waitcnt vmcnt(0)" ::: "memory");
        }
        __builtin_amdgcn_sched_barrier(0);
        __builtin_amdgcn_s_barrier();

        short8 bfr[4][2];
#pragma unroll
        for (int n = 0; n < 4; ++n)
#pragma unroll
            for (int ks = 0; ks < 2; ++ks) {
                int col = wc * 64 + n * 16 + lr;
                bfr[n][ks] = *(const short8*)&Bs[c][col * 64 + (((ks * 4 + g) ^ (lr & 7)) << 3)];
            }
        short8 af[4][2];
#pragma unroll
        for (int m = 0; m < 4; ++m)
#pragma unroll
            for (int ks = 0; ks < 2; ++ks) {
                int row = wr * 64 + m * 16 + lr;
                af[m][ks] = *(const short8*)&As[c][row * 64 + (((ks * 4 + g) ^ (lr & 7)) << 3)];
            }
        __builtin_amdgcn_s_setprio(1);
#pragma unroll
        for (int m = 0; m < 4; ++m)
#pragma unroll
            for (int n = 0; n < 4; ++n) {
                acc[m][n] = __builtin_amdgcn_mfma_f32_16x16x32_bf16(af[m][0], bfr[n][0], acc[m][n], 0, 0, 0);
                acc[m][n] = __builtin_amdgcn_mfma_f32_16x16x32_bf16(af[m][1], bfr[n][1], acc[m][n], 0, 0, 0);
            }
        __builtin_amdgcn_s_setprio(0);

        __builtin_amdgcn_sched_barrier(0);
        __builtin_amdgcn_s_barrier();
    }

#pragma unroll
    for (int n = 0; n < 4; ++n) {
        int col = nbase + wc * 64 + n * 16 + lr;
        float bv = (col < 1024) ? ldbias(bq, col, ofp) : ldbias(bkv, col - 1024, ofp);
#pragma unroll
        for (int m = 0; m < 4; ++m) {
            int rowb = mbase + wr * 64 + m * 16 + g * 4;
#pragma unroll
            for (int i = 0; i < 4; ++i) {
                int r = rowb + i;
                if (r >= MU) continue;
                float val = acc[m][n][i] + bv;
                if (col < 1024) {
                    if (r >= 256) q_ws[(size_t)(r - 256) * 1024 + col] = f2b(val * QSCALE);
                } else {
                    if (r < 4608) {
                        kv_ws[(size_t)r * 2048 + (col - 1024)] = f2b(val);
                        if (r >= 512) {
                            size_t o = (col < 2048)
                                ? OUTK + (size_t)(r - 512) * 1024 + (col - 1024)
                                : OUTV + (size_t)(r - 512) * 1024 + (col - 2048);
                            stout(gout, o, val, ofp);
                        }
                    }
                }
            }
        }
    }
}

// ---------------------------------------------------------------- out GEMM: 64x128 tile, BK=64, 4 waves
// 48KB LDS -> 3 blocks/CU; k-contiguous 128B staging; counted vmcnt(6).
#define O_STAGE(DSTBUF, KT)                                                           \
    _Pragma("unroll")                                                                 \
    for (int i2 = 0; i2 < 2; ++i2)                                                    \
        gload_lds16(asrc[i2] + (KT) * 64, &As[DSTBUF][(i2 * 256 + t) * 8]);           \
    _Pragma("unroll")                                                                 \
    for (int i2 = 0; i2 < 4; ++i2)                                                    \
        gload_lds16(bsrc[i2] + (KT) * 64, &Bs[DSTBUF][(i2 * 256 + t) * 8]);

__global__ __launch_bounds__(256, 3) void gemm_out(
    const ushort* __restrict__ A, const ushort* __restrict__ Bt,
    const void* __restrict__ bias, void* __restrict__ gout, const int* __restrict__ flags) {
    __shared__ alignas(16) ushort As[2][4096];   // [64 rows][64 k] x2 = 16 KB
    __shared__ alignas(16) ushort Bs[2][8192];   // [128 rows][64 k] x2 = 32 KB
    const int ofp = flags[0];
    const int t = threadIdx.x;
    const int lane = t & 63;
    const int w = t >> 6;
    const int wr = w >> 1, wc = w & 1;
    const int g = lane >> 4, lr = lane & 15;

    const int nwg = gridDim.x;                   // 552, %8 == 0
    const int bid = blockIdx.x;
    const int wg = (bid & 7) * (nwg >> 3) + (bid >> 3);
    const int bx = wg % 8, by = wg / 8;
    const int mbase = by * 64, nbase = bx * 128;   // 69*64 = 4416 exact

    const ushort* asrc[2];
#pragma unroll
    for (int i2 = 0; i2 < 2; ++i2) {
        int slot = i2 * 256 + t;
        int row = slot >> 3, kc = slot & 7, q = kc ^ (row & 7);
        asrc[i2] = A + (size_t)(mbase + row) * 1024 + q * 8;
    }
    const ushort* bsrc[4];
#pragma unroll
    for (int i2 = 0; i2 < 4; ++i2) {
        int slot = i2 * 256 + t;
        int row = slot >> 3, kc = slot & 7, q = kc ^ (row & 7);
        bsrc[i2] = Bt + (size_t)(nbase + row) * 1024 + q * 8;
    }

    f32x4 acc[2][4] = {};

    O_STAGE(0, 0);

    for (int kt = 0; kt < 16; ++kt) {
        const int c = kt & 1;
        if (kt + 1 < 16) {
            O_STAGE(c ^ 1, kt + 1);
            asm volatile("s_waitcnt vmcnt(6)" ::: "memory");
        } else {
            asm volatile("s_waitcnt vmcnt(0)" ::: "memory");
        }
        __builtin_amdgcn_sched_barrier(0);
        __builtin_amdgcn_s_barrier();

        short8 bfr[4][2];
#pragma unroll
        for (int n = 0; n < 4; ++n)
#pragma unroll
            for (int ks = 0; ks < 2; ++ks) {
                int col = wc * 64 + n * 16 + lr;
                bfr[n][ks] = *(const short8*)&Bs[c][col * 64 + (((ks * 4 + g) ^ (lr & 7)) << 3)];
            }
        short8 af[2][2];
#pragma unroll
        for (int m = 0; m < 2; ++m)
#pragma unroll
            for (int ks = 0; ks < 2; ++ks) {
                int row = wr * 32 + m * 16 + lr;
                af[m][ks] = *(const short8*)&As[c][row * 64 + (((ks * 4 + g) ^ (lr & 7)) << 3)];
            }
        __builtin_amdgcn_s_setprio(1);
#pragma unroll
        for (int m = 0; m < 2; ++m)
#pragma unroll
            for (int n = 0; n < 4; ++n) {
                acc[m][n] = __builtin_amdgcn_mfma_f32_16x16x32_bf16(af[m][0], bfr[n][0], acc[m][n], 0, 0, 0);
                acc[m][n] = __builtin_amdgcn_mfma_f32_16x16x32_bf16(af[m][1], bfr[n][1], acc[m][n], 0, 0, 0);
            }
        __builtin_amdgcn_s_setprio(0);

        __builtin_amdgcn_sched_barrier(0);
        __builtin_amdgcn_s_barrier();
    }

#pragma unroll
    for (int n = 0; n < 4; ++n) {
        int col = nbase + wc * 64 + n * 16 + lr;
        float bv = ldbias(bias, col, ofp);
#pragma unroll
        for (int m = 0; m < 2; ++m) {
            int rowb = mbase + wr * 32 + m * 16 + g * 4;
#pragma unroll
            for (int i = 0; i < 4; ++i) {
                int row = rowb + i;
                float val = acc[m][n][i] + bv;
                if (row < (Rn + Tn) * Bn) stout(gout, (size_t)row * 1024 + col, val, ofp);
                else stout(gout, OUTM + (size_t)(row - (Rn + Tn) * Bn) * 1024 + col, tanhf(val), ofp);
            }
        }
    }
}

// ---------------------------------------------------------------- attention
#define ATTN_STAGE(DSTBUF, KT)                                                        \
    gload_lds16(ksrc0 + (size_t)(KT) * kstep, &Ks[DSTBUF][w * 1024]);                 \
    gload_lds16(ksrc1 + (size_t)(KT) * kstep, &Ks[DSTBUF][w * 1024 + 512]);           \
    gload_lds16(vsrc0 + (size_t)(KT) * 64,    &Vs[DSTBUF][w * 1024]);                 \
    gload_lds16(vsrc1 + (size_t)(KT) * 64,    &Vs[DSTBUF][w * 1024 + 512]);

#define ATTN_PHASE(CUR, WBCUR, PRE, KTN, WBNXT, VMSTR)                                \
    {                                                                                 \
        if (PRE) { ATTN_STAGE((CUR) ^ 1, KTN); WBNXT = mp[KTN]; }                     \
        asm volatile("s_waitcnt " VMSTR ::: "memory");                                \
        __builtin_amdgcn_sched_barrier(0);                                            \
        __builtin_amdgcn_s_barrier();                                                 \
        __builtin_amdgcn_sched_barrier(0);                                            \
        f32x4 sa[4] = {};                                                             \
        __builtin_amdgcn_s_setprio(1);                                                \
        _Pragma("unroll")                                                             \
        for (int n = 0; n < 4; ++n) {                                                 \
            int key = n * 16 + lr;                                                    \
            short8 kb0 = *(const short8*)&Ks[CUR][key * 64 + ((g ^ (key & 7)) << 3)]; \
            short8 kb1 = *(const short8*)&Ks[CUR][key * 64 + (((4 + g) ^ (key & 7)) << 3)]; \
            sa[n] = __builtin_amdgcn_mfma_f32_16x16x32_bf16(kb0, qf0, sa[n], 0, 0, 0); \
            sa[n] = __builtin_amdgcn_mfma_f32_16x16x32_bf16(kb1, qf1, sa[n], 0, 0, 0); \
        }                                                                             \
        __builtin_amdgcn_s_setprio(0);                                                \
        unsigned pkk[4][2];                                                           \
        _Pragma("unroll")                                                             \
        for (int n = 0; n < 4; ++n) {                                                 \
            unsigned bits = (unsigned)((WBCUR) >> (n * 16 + g * 4)) & 15u;            \
            float p[4];                                                               \
            _Pragma("unroll")                                                         \
            for (int i = 0; i < 4; ++i) {                                             \
                float sv = ((bits >> i) & 1u) ? -100.0f : sa[n][i];                   \
                p[i] = exp2f(sv);                                                     \
                lsum += p[i];                                                         \
            }                                                                         \
            pkk[n][0] = cvt_pk_bf16(p[0], p[1]);                                      \
            pkk[n][1] = cvt_pk_bf16(p[2], p[3]);                                      \
        }                                                                             \
        union { unsigned u[4]; short8 s; } c0, c1;                                    \
        c0.u[0] = pkk[0][0]; c0.u[1] = pkk[0][1]; c0.u[2] = pkk[1][0]; c0.u[3] = pkk[1][1]; \
        c1.u[0] = pkk[2][0]; c1.u[1] = pkk[2][1]; c1.u[2] = pkk[3][0]; c1.u[3] = pkk[3][1]; \
        __builtin_amdgcn_s_setprio(1);                                                \
        _Pragma("unroll")                                                             \
        for (int n = 0; n < 4; ++n) {                                                 \
            int d = n * 16 + lr;                                                      \
            short8 vb0 = *(const short8*)&Vs[CUR][d * 64 + ((g ^ (d & 7)) << 3)];     \
            short8 vb1 = *(const short8*)&Vs[CUR][d * 64 + (((4 + g) ^ (d & 7)) << 3)]; \
            acc_o[n] = __builtin_amdgcn_mfma_f32_16x16x32_bf16(c0.s, vb0, acc_o[n], 0, 0, 0); \
            acc_o[n] = __builtin_amdgcn_mfma_f32_16x16x32_bf16(c1.s, vb1, acc_o[n], 0, 0, 0); \
        }                                                                             \
        __builtin_amdgcn_s_setprio(0);                                                \
        __builtin_amdgcn_sched_barrier(0);                                            \
        __builtin_amdgcn_s_barrier();                                                 \
    }

__global__ __launch_bounds__(256, 5) void attn_kernel(
    const ushort* __restrict__ qws, const ushort* __restrict__ kvws, const ushort* __restrict__ vTws,
    const unsigned long long* __restrict__ mbits,
    ushort* __restrict__ attnws) {
    __shared__ alignas(16) ushort Ks[2][64 * 64];
    __shared__ alignas(16) ushort Vs[2][64 * 64];

    const int bid = blockIdx.x;
    const int wg = (bid & 7) * (gridDim.x >> 3) + (bid >> 3);
    const int qblk = wg % NQB;
    const int bh = wg / NQB;
    const int b = bh >> 4, h = bh & 15;
    const int t = threadIdx.x;
    const int w = t >> 6, lane = t & 63;
    const int g = lane >> 4, lr = lane & 15;

    const int qi = qblk * 64 + w * 16 + lr;
    const int qic = qi < Qn ? qi : (Qn - 1);
    const ushort* qptr = qws + ((size_t)qic * Bn + b) * Dn + h * DH;
    const short8 qf0 = *(const short8*)(qptr + g * 8);
    const short8 qf1 = *(const short8*)(qptr + 32 + g * 8);
    const unsigned long long* mp = mbits + ((size_t)b * Qn + qic) * NT;

    const int srow0 = w * 16 + (lane >> 3);
    const int srow1 = srow0 + 8;
    const int sw = (((lane & 7) ^ ((lane >> 3) & 7)) << 3);
    const ushort* ksrc0 = kvws + ((size_t)srow0 * Bn + b) * 2048 + h * DH + sw;
    const ushort* ksrc1 = kvws + ((size_t)srow1 * Bn + b) * 2048 + h * DH + sw;
    const ushort* vsrc0 = vTws + ((size_t)bh * 64 + srow0) * KL + sw;
    const ushort* vsrc1 = vTws + ((size_t)bh * 64 + srow1) * KL + sw;
    const size_t kstep = (size_t)64 * Bn * 2048;

    f32x4 acc_o[4] = {};
    float lsum = 0.f;
    unsigned long long wbA, wbB;

    ATTN_STAGE(0, 0);
    wbA = mp[0];
    wbB = 0;

    for (int kt2 = 0; kt2 < NT - 2; kt2 += 2) {
        ATTN_PHASE(0, wbA, true, kt2 + 1, wbB, "vmcnt(4)");
        ATTN_PHASE(1, wbB, true, kt2 + 2, wbA, "vmcnt(4)");
    }
    ATTN_PHASE(0, wbA, true, NT - 1, wbB, "vmcnt(4)");
    ATTN_PHASE(1, wbB, false, 0, wbA, "vmcnt(0)");

    float ls = lsum;
    ls += __shfl_xor(ls, 16);
    ls += __shfl_xor(ls, 32);
#pragma unroll
    for (int i = 0; i < 4; ++i) {
        int qrow = g * 4 + i;
        float lsv = __shfl(ls, (lane & 48) | qrow);
        int qg = qblk * 64 + w * 16 + qrow;
        if (qg >= Qn) continue;
        float inv = 1.f / lsv;
#pragma unroll
        for (int n = 0; n < 4; ++n) {
            attnws[((size_t)qg * Bn + b) * Dn + h * DH + n * 16 + lr] = f2b(acc_o[n][i] * inv);
        }
    }
}

// ---------------------------------------------------------------- launch
extern "C" void kernel_launch(void* const* d_in, const int* in_sizes, int n_in,
                              void* d_out, int out_size, void* d_ws, size_t ws_size,
                              hipStream_t stream) {
    const void* utt   = d_in[0];
    const void* rc    = d_in[1];
    const void* summ  = d_in[2];
    const void* mems  = d_in[3];
    const int*  lens  = (const int*)d_in[4];
    const void* amask = d_in[5];
    const void* Wq   = d_in[6];
    const void* bq   = d_in[7];
    const void* Wkv  = d_in[8];
    const void* bkv  = d_in[9];
    const void* Wout = d_in[10];
    const void* bout = d_in[11];

    ushort* ws    = (ushort*)d_ws;
    int*   flags  = (int*)d_ws;
    ushort* cu    = ws + 64;
    ushort* cutt  = cu;
    ushort* crc   = cutt + NU;
    ushort* csum  = crc + NR_;
    ushort* cmem  = csum + NS_;
    ushort* WqT   = cmem + NM_;                      // WqT then WkvT contiguous = fused (3072 x 1024) Bt
    ushort* WkvT  = WqT + (size_t)1024 * 1024;
    ushort* WoutT = WkvT + (size_t)2048 * 1024;
    ushort* q_ws  = WoutT + (size_t)1024 * 1024;
    ushort* kv_ws = q_ws + (size_t)QB * Dn;
    ushort* vT_ws = kv_ws + (size_t)KB * 2048;
    ushort* at_ws = vT_ws + (size_t)64 * 64 * KL;
    unsigned long long* mbits = (unsigned long long*)(at_ws + (size_t)QB * Dn);  // Bn*Qn*NT words

    probe_kernel<<<1, 256, 0, stream>>>((const ushort*)utt, (const unsigned char*)amask, flags);
    prep_kernel<<<PREP_TW + PREP_CV + PREP_MB, 256, 0, stream>>>(
        utt, rc, summ, mems, Wq, Wkv, Wout, amask, lens,
        cu, WqT, WkvT, WoutT, mbits, flags);

    gemm_qkv<<<dim3(888), 256, 0, stream>>>(cmem, crc, cutt, csum, WqT, bq, bkv,
                                            q_ws, kv_ws, d_out, flags);
    transpose_v<<<dim3(KL / 64, Bn * Hn), 256, 0, stream>>>(kv_ws, vT_ws);
    attn_kernel<<<dim3(NQB * Bn * Hn), 256, 0, stream>>>(q_ws, kv_ws, vT_ws, mbits, at_ws);
    gemm_out<<<dim3(552), 256, 0, stream>>>(at_ws, WoutT, bout, d_out, flags);
}